// Round 1
// baseline (124.462 us; speedup 1.0000x reference)
//
#include <hip/hip_runtime.h>
#include <math.h>

// MDN_module: B rows, each: h = relu(x@W1 + b1) [64], out = h@W2 + b2 [4]
// mu = out[0:2], lv = out[2:4] (log-variance); Lyapunov rescale; rsample fx;
// accumulate logp_y = sum over rows of 0.5*(d0^2/var0 + d1^2/var1 + lv0 + lv1 + 2*log(2pi))
//
// Layout notes:
//   W1 [2][64] row-major: W1[0][j]=W1[j], W1[1][j]=W1[64+j]
//   W2 [64][4] row-major: one float4 per hidden unit j
//   Wv [2][2]: (z@Wv)_k = z0*Wv[0*2+k] + z1*Wv[1*2+k]
//   d_out: fx (2B floats) then logp_y (1 float at index 2B)

#define GRID 1024
#define BLOCK 256
#define PPT 4              // float4 row-pairs per thread -> 8 rows/thread
#define LOG_2PI 1.8378770664093453f

__device__ __forceinline__ float rcp_fast(float v) { return __builtin_amdgcn_rcpf(v); }

__launch_bounds__(BLOCK, 4)
__global__ void mdn_kernel(const float* __restrict__ x,
                           const float* __restrict__ y,
                           const float* __restrict__ eps,
                           const float* __restrict__ W1,
                           const float* __restrict__ b1,
                           const float* __restrict__ W2,
                           const float* __restrict__ b2,
                           const float* __restrict__ Wv,
                           float* __restrict__ fx_out,
                           float* __restrict__ logp_out,
                           int n_pairs)
{
    __shared__ float s_w1a[64];
    __shared__ float s_w1b[64];
    __shared__ float s_b1[64];
    __shared__ float s_w2[64][4];
    __shared__ float s_part[BLOCK / 64];

    const int t = threadIdx.x;
    if (t < 64) {
        s_w1a[t] = W1[t];
        s_w1b[t] = W1[64 + t];
        s_b1[t]  = b1[t];
        const float4 w2v = reinterpret_cast<const float4*>(W2)[t];
        s_w2[t][0] = w2v.x; s_w2[t][1] = w2v.y; s_w2[t][2] = w2v.z; s_w2[t][3] = w2v.w;
    }
    // wave-uniform scalars -> s_load
    const float b2_0 = b2[0], b2_1 = b2[1], b2_2 = b2[2], b2_3 = b2[3];
    const float wv00 = Wv[0], wv01 = Wv[1], wv10 = Wv[2], wv11 = Wv[3];
    __syncthreads();

    const int T = GRID * BLOCK;
    const int g = blockIdx.x * BLOCK + t;

    float x0[2 * PPT], x1[2 * PPT];
    float a0[2 * PPT], a1[2 * PPT], a2[2 * PPT], a3[2 * PPT];

    #pragma unroll
    for (int p = 0; p < PPT; ++p) {
        const int rp = g + p * T;
        float4 xv = make_float4(0.f, 0.f, 0.f, 0.f);
        if (rp < n_pairs) xv = reinterpret_cast<const float4*>(x)[rp];
        x0[2 * p]     = xv.x; x1[2 * p]     = xv.y;
        x0[2 * p + 1] = xv.z; x1[2 * p + 1] = xv.w;
    }
    #pragma unroll
    for (int r = 0; r < 2 * PPT; ++r) {
        a0[r] = b2_0; a1[r] = b2_1; a2[r] = b2_2; a3[r] = b2_3;
    }

    // main MLP loop: 16 chunks of 4 hidden units, weights hoisted via ds_read_b128
    for (int c = 0; c < 16; ++c) {
        const float4 wa  = *reinterpret_cast<const float4*>(&s_w1a[4 * c]);
        const float4 wb  = *reinterpret_cast<const float4*>(&s_w1b[4 * c]);
        const float4 bb  = *reinterpret_cast<const float4*>(&s_b1[4 * c]);
        const float4 w20 = *reinterpret_cast<const float4*>(&s_w2[4 * c + 0][0]);
        const float4 w21 = *reinterpret_cast<const float4*>(&s_w2[4 * c + 1][0]);
        const float4 w22 = *reinterpret_cast<const float4*>(&s_w2[4 * c + 2][0]);
        const float4 w23 = *reinterpret_cast<const float4*>(&s_w2[4 * c + 3][0]);
        #pragma unroll
        for (int r = 0; r < 2 * PPT; ++r) {
            float h;
            h = fmaxf(fmaf(x0[r], wa.x, fmaf(x1[r], wb.x, bb.x)), 0.f);
            a0[r] = fmaf(h, w20.x, a0[r]); a1[r] = fmaf(h, w20.y, a1[r]);
            a2[r] = fmaf(h, w20.z, a2[r]); a3[r] = fmaf(h, w20.w, a3[r]);
            h = fmaxf(fmaf(x0[r], wa.y, fmaf(x1[r], wb.y, bb.y)), 0.f);
            a0[r] = fmaf(h, w21.x, a0[r]); a1[r] = fmaf(h, w21.y, a1[r]);
            a2[r] = fmaf(h, w21.z, a2[r]); a3[r] = fmaf(h, w21.w, a3[r]);
            h = fmaxf(fmaf(x0[r], wa.z, fmaf(x1[r], wb.z, bb.z)), 0.f);
            a0[r] = fmaf(h, w22.x, a0[r]); a1[r] = fmaf(h, w22.y, a1[r]);
            a2[r] = fmaf(h, w22.z, a2[r]); a3[r] = fmaf(h, w22.w, a3[r]);
            h = fmaxf(fmaf(x0[r], wa.w, fmaf(x1[r], wb.w, bb.w)), 0.f);
            a0[r] = fmaf(h, w23.x, a0[r]); a1[r] = fmaf(h, w23.y, a1[r]);
            a2[r] = fmaf(h, w23.z, a2[r]); a3[r] = fmaf(h, w23.w, a3[r]);
        }
    }

    // epilogue: Lyapunov rescale, rsample, logp
    float lsum = 0.f;
    #pragma unroll
    for (int p = 0; p < PPT; ++p) {
        const int rp = g + p * T;
        if (rp >= n_pairs) continue;
        const float4 yv = reinterpret_cast<const float4*>(y)[rp];
        const float4 ev = reinterpret_cast<const float4*>(eps)[rp];
        float4 fxv;
        #pragma unroll
        for (int hh = 0; hh < 2; ++hh) {
            const int r = 2 * p + hh;
            const float mu0 = a0[r], mu1 = a1[r];
            const float lv0 = a2[r], lv1 = a3[r];
            const float y0 = hh ? yv.z : yv.x;
            const float y1 = hh ? yv.w : yv.y;
            const float e0 = hh ? ev.z : ev.x;
            const float e1 = hh ? ev.w : ev.y;
            // V(x) and V(mu)
            const float zx0 = fmaf(x0[r], wv00, x1[r] * wv10);
            const float zx1 = fmaf(x0[r], wv01, x1[r] * wv11);
            const float Vx  = fmaf(zx0, zx0, fmaf(zx1, zx1, 1e-3f));
            const float zm0 = fmaf(mu0, wv00, mu1 * wv10);
            const float zm1 = fmaf(mu0, wv01, mu1 * wv11);
            const float Vmu = fmaf(zm0, zm0, fmaf(zm1, zm1, 1e-3f));
            // scale = min(beta*Vx, Vmu)/Vmu
            const float scale = fminf(0.99f * Vx, Vmu) * rcp_fast(Vmu);
            const float ms0 = mu0 * scale, ms1 = mu1 * scale;
            // rsample: fx = ms + exp(lv/2)*eps
            const float s0 = __expf(0.5f * lv0);
            const float s1 = __expf(0.5f * lv1);
            const float f0 = fmaf(s0, e0, ms0);
            const float f1 = fmaf(s1, e1, ms1);
            if (hh) { fxv.z = f0; fxv.w = f1; }
            else    { fxv.x = f0; fxv.y = f1; }
            // -logp = 0.5*(d0^2/var0 + d1^2/var1 + lv0 + lv1) + log(2pi)
            const float d0 = y0 - ms0;
            const float d1 = y1 - ms1;
            const float iv0 = __expf(-lv0);
            const float iv1 = __expf(-lv1);
            const float q = fmaf(d0 * d0, iv0, d1 * d1 * iv1);
            lsum += fmaf(0.5f, q + lv0 + lv1, LOG_2PI);
        }
        reinterpret_cast<float4*>(fx_out)[rp] = fxv;
    }

    // reduce lsum: wave shuffle -> LDS -> one atomic per block
    #pragma unroll
    for (int off = 32; off; off >>= 1) lsum += __shfl_xor(lsum, off, 64);
    if ((t & 63) == 0) s_part[t >> 6] = lsum;
    __syncthreads();
    if (t == 0) {
        float bs = 0.f;
        #pragma unroll
        for (int w = 0; w < BLOCK / 64; ++w) bs += s_part[w];
        atomicAdd(logp_out, bs);
    }
}

extern "C" void kernel_launch(void* const* d_in, const int* in_sizes, int n_in,
                              void* d_out, int out_size, void* d_ws, size_t ws_size,
                              hipStream_t stream) {
    const float* x   = (const float*)d_in[0];
    const float* y   = (const float*)d_in[1];
    const float* eps = (const float*)d_in[2];
    const float* W1  = (const float*)d_in[3];
    const float* b1  = (const float*)d_in[4];
    const float* W2  = (const float*)d_in[5];
    const float* b2  = (const float*)d_in[6];
    const float* Wv  = (const float*)d_in[7];

    const int B = in_sizes[0] / 2;          // rows
    const int n_pairs = B / 2;              // float4 row-pairs
    float* fx_out   = (float*)d_out;
    float* logp_out = fx_out + (size_t)2 * B;   // scalar at flat index 2B

    hipMemsetAsync(logp_out, 0, sizeof(float), stream);
    mdn_kernel<<<GRID, BLOCK, 0, stream>>>(x, y, eps, W1, b1, W2, b2, Wv,
                                           fx_out, logp_out, n_pairs);
}

// Round 2
// 121.644 us; speedup vs baseline: 1.0232x; 1.0232x over previous
//
#include <hip/hip_runtime.h>
#include <math.h>

// MDN_module: B rows, each: h = relu(x@W1 + b1) [64], out = h@W2 + b2 [4]
// mu = out[0:2], lv = out[2:4]; Lyapunov rescale; rsample fx; grand-sum logp_y.
//
// R2 strategy: weights are wave-uniform -> keep them OUT of LDS/VMEM-per-lane.
// Uniform loads from const __restrict__ pointers become s_load_dwordx4 (SMEM
// pipe, free wrt VALU/LDS). Row math packed 2-wide (v_pk_fma_f32) over the
// two rows of each float4: MLP 7 scalar inst/row -> 7 pk inst/row-pair.
//
//   W1 [2][64] row-major; W2 [64][4] row-major (float4/row); Wv [2][2]
//   d_out: fx (2B floats) then logp_y (1 float at index 2B)

typedef float v2f __attribute__((ext_vector_type(2)));

#define GRID 1024
#define BLOCK 256
#define NPAIR 4            // float4 row-pairs per thread -> 8 rows/thread (exact fit)
#define LOG_2PI 1.8378770664093453f

__device__ __forceinline__ float rcp_fast(float v) { return __builtin_amdgcn_rcpf(v); }
__device__ __forceinline__ v2f splat(float s) { v2f r; r.x = s; r.y = s; return r; }

__launch_bounds__(BLOCK, 4)
__global__ void mdn_kernel(const float* __restrict__ x,
                           const float* __restrict__ y,
                           const float* __restrict__ eps,
                           const float* __restrict__ W1,
                           const float* __restrict__ b1,
                           const float* __restrict__ W2,
                           const float* __restrict__ b2,
                           const float* __restrict__ Wv,
                           float* __restrict__ fx_out,
                           float* __restrict__ logp_out,
                           int n_pairs)
{
    __shared__ float s_part[BLOCK / 64];

    const int t = threadIdx.x;
    const int T = GRID * BLOCK;
    const int g = blockIdx.x * BLOCK + t;

    // uniform scalars -> s_load
    const float b2_0 = b2[0], b2_1 = b2[1], b2_2 = b2[2], b2_3 = b2[3];
    const float wv00 = Wv[0], wv01 = Wv[1], wv10 = Wv[2], wv11 = Wv[3];

    // X0/X1: x-components of the 2 rows in each float4, packed.
    v2f X0[NPAIR], X1[NPAIR];
    v2f A0[NPAIR], A1[NPAIR], A2[NPAIR], A3[NPAIR];

    #pragma unroll
    for (int p = 0; p < NPAIR; ++p) {
        const int rp = g + p * T;
        float4 xv = make_float4(0.f, 0.f, 0.f, 0.f);
        if (rp < n_pairs) xv = reinterpret_cast<const float4*>(x)[rp];
        X0[p].x = xv.x; X0[p].y = xv.z;   // rows 2rp, 2rp+1: x[0]
        X1[p].x = xv.y; X1[p].y = xv.w;   // rows 2rp, 2rp+1: x[1]
        A0[p] = splat(b2_0); A1[p] = splat(b2_1);
        A2[p] = splat(b2_2); A3[p] = splat(b2_3);
    }

    // Main MLP loop: 16 chunks x 4 hidden units. All weight addresses are
    // wave-uniform -> SMEM scalar loads; no LDS, no per-lane VMEM.
    #pragma unroll 2
    for (int c = 0; c < 16; ++c) {
        const float4 wa = *reinterpret_cast<const float4*>(W1 + 4 * c);        // W1[0][4c..]
        const float4 wb = *reinterpret_cast<const float4*>(W1 + 64 + 4 * c);   // W1[1][4c..]
        const float4 bb = *reinterpret_cast<const float4*>(b1 + 4 * c);
        const float4 w2r[4] = {
            reinterpret_cast<const float4*>(W2)[4 * c + 0],
            reinterpret_cast<const float4*>(W2)[4 * c + 1],
            reinterpret_cast<const float4*>(W2)[4 * c + 2],
            reinterpret_cast<const float4*>(W2)[4 * c + 3],
        };
        #pragma unroll
        for (int j = 0; j < 4; ++j) {
            const v2f waj = splat((&wa.x)[j]);
            const v2f wbj = splat((&wb.x)[j]);
            const v2f bj  = splat((&bb.x)[j]);
            const v2f w20 = splat(w2r[j].x);
            const v2f w21 = splat(w2r[j].y);
            const v2f w22 = splat(w2r[j].z);
            const v2f w23 = splat(w2r[j].w);
            #pragma unroll
            for (int p = 0; p < NPAIR; ++p) {
                v2f h = __builtin_elementwise_fma(X1[p], wbj, bj);
                h = __builtin_elementwise_fma(X0[p], waj, h);
                h = __builtin_elementwise_max(h, splat(0.f));
                A0[p] = __builtin_elementwise_fma(h, w20, A0[p]);
                A1[p] = __builtin_elementwise_fma(h, w21, A1[p]);
                A2[p] = __builtin_elementwise_fma(h, w22, A2[p]);
                A3[p] = __builtin_elementwise_fma(h, w23, A3[p]);
            }
        }
    }

    // Epilogue: Lyapunov rescale, rsample, logp (scalar per row; exp/rcp
    // have no packed form anyway).
    float lsum = 0.f;
    #pragma unroll
    for (int p = 0; p < NPAIR; ++p) {
        const int rp = g + p * T;
        if (rp >= n_pairs) continue;
        const float4 yv = reinterpret_cast<const float4*>(y)[rp];
        const float4 ev = reinterpret_cast<const float4*>(eps)[rp];
        float4 fxv;
        #pragma unroll
        for (int hh = 0; hh < 2; ++hh) {
            const float mu0 = hh ? A0[p].y : A0[p].x;
            const float mu1 = hh ? A1[p].y : A1[p].x;
            const float lv0 = hh ? A2[p].y : A2[p].x;
            const float lv1 = hh ? A3[p].y : A3[p].x;
            const float xx0 = hh ? X0[p].y : X0[p].x;
            const float xx1 = hh ? X1[p].y : X1[p].x;
            const float y0 = hh ? yv.z : yv.x;
            const float y1 = hh ? yv.w : yv.y;
            const float e0 = hh ? ev.z : ev.x;
            const float e1 = hh ? ev.w : ev.y;
            // V(x), V(mu)
            const float zx0 = fmaf(xx0, wv00, xx1 * wv10);
            const float zx1 = fmaf(xx0, wv01, xx1 * wv11);
            const float Vx  = fmaf(zx0, zx0, fmaf(zx1, zx1, 1e-3f));
            const float zm0 = fmaf(mu0, wv00, mu1 * wv10);
            const float zm1 = fmaf(mu0, wv01, mu1 * wv11);
            const float Vmu = fmaf(zm0, zm0, fmaf(zm1, zm1, 1e-3f));
            // scale = min(beta*Vx, Vmu)/Vmu
            const float scale = fminf(0.99f * Vx, Vmu) * rcp_fast(Vmu);
            const float ms0 = mu0 * scale, ms1 = mu1 * scale;
            // rsample: fx = ms + exp(lv/2)*eps
            const float f0 = fmaf(__expf(0.5f * lv0), e0, ms0);
            const float f1 = fmaf(__expf(0.5f * lv1), e1, ms1);
            if (hh) { fxv.z = f0; fxv.w = f1; }
            else    { fxv.x = f0; fxv.y = f1; }
            // -logp contribution
            const float d0 = y0 - ms0;
            const float d1 = y1 - ms1;
            const float q = fmaf(d0 * d0, __expf(-lv0), d1 * d1 * __expf(-lv1));
            lsum += fmaf(0.5f, q + lv0 + lv1, LOG_2PI);
        }
        reinterpret_cast<float4*>(fx_out)[rp] = fxv;
    }

    // reduce lsum: wave shuffle -> LDS -> one atomic per block
    #pragma unroll
    for (int off = 32; off; off >>= 1) lsum += __shfl_xor(lsum, off, 64);
    if ((t & 63) == 0) s_part[t >> 6] = lsum;
    __syncthreads();
    if (t == 0) {
        float bs = 0.f;
        #pragma unroll
        for (int w = 0; w < BLOCK / 64; ++w) bs += s_part[w];
        atomicAdd(logp_out, bs);
    }
}

extern "C" void kernel_launch(void* const* d_in, const int* in_sizes, int n_in,
                              void* d_out, int out_size, void* d_ws, size_t ws_size,
                              hipStream_t stream) {
    const float* x   = (const float*)d_in[0];
    const float* y   = (const float*)d_in[1];
    const float* eps = (const float*)d_in[2];
    const float* W1  = (const float*)d_in[3];
    const float* b1  = (const float*)d_in[4];
    const float* W2  = (const float*)d_in[5];
    const float* b2  = (const float*)d_in[6];
    const float* Wv  = (const float*)d_in[7];

    const int B = in_sizes[0] / 2;          // rows
    const int n_pairs = B / 2;              // float4 row-pairs
    float* fx_out   = (float*)d_out;
    float* logp_out = fx_out + (size_t)2 * B;   // scalar at flat index 2B

    hipMemsetAsync(logp_out, 0, sizeof(float), stream);
    mdn_kernel<<<GRID, BLOCK, 0, stream>>>(x, y, eps, W1, b1, W2, b2, Wv,
                                           fx_out, logp_out, n_pairs);
}

// Round 3
// 120.510 us; speedup vs baseline: 1.0328x; 1.0094x over previous
//
#include <hip/hip_runtime.h>
#include <math.h>

// MDN_module: B rows, each: h = relu(x@W1 + b1) [64], out = h@W2 + b2 [4]
// mu = out[0:2], lv = out[2:4]; Lyapunov rescale; rsample fx; grand-sum logp_y.
//
// R3 strategy (on top of R2's s_load weights + packed v2f MLP):
//  1. Hoist ALL global loads (x, y, eps float4s) to kernel entry so the
//     ~900-cyc HBM latency hides under the ~3600-cyc MLP compute, instead of
//     stalling per-pair in the epilogue.
//  2. Replace 1024 same-address atomicAdds + memset dispatch with per-block
//     partials in d_ws + a tiny reduce kernel (no atomic serialization tail).
//
//   W1 [2][64] row-major; W2 [64][4] row-major (float4/row); Wv [2][2]
//   d_out: fx (2B floats) then logp_y (1 float at index 2B)

typedef float v2f __attribute__((ext_vector_type(2)));

#define GRID 1024
#define BLOCK 256
#define NPAIR 4            // float4 row-pairs per thread -> 8 rows/thread (exact fit)
#define LOG_2PI 1.8378770664093453f

__device__ __forceinline__ float rcp_fast(float v) { return __builtin_amdgcn_rcpf(v); }
__device__ __forceinline__ v2f splat(float s) { v2f r; r.x = s; r.y = s; return r; }

__launch_bounds__(BLOCK, 4)
__global__ void mdn_kernel(const float* __restrict__ x,
                           const float* __restrict__ y,
                           const float* __restrict__ eps,
                           const float* __restrict__ W1,
                           const float* __restrict__ b1,
                           const float* __restrict__ W2,
                           const float* __restrict__ b2,
                           const float* __restrict__ Wv,
                           float* __restrict__ fx_out,
                           float* __restrict__ block_part,
                           int n_pairs)
{
    __shared__ float s_part[BLOCK / 64];

    const int t = threadIdx.x;
    const int T = GRID * BLOCK;
    const int g = blockIdx.x * BLOCK + t;

    // uniform scalars -> s_load
    const float b2_0 = b2[0], b2_1 = b2[1], b2_2 = b2[2], b2_3 = b2[3];
    const float wv00 = Wv[0], wv01 = Wv[1], wv10 = Wv[2], wv11 = Wv[3];

    // ---- hoist ALL global loads up front (latency hides under MLP) ----
    float4 yv[NPAIR], ev[NPAIR];
    v2f X0[NPAIR], X1[NPAIR];
    v2f A0[NPAIR], A1[NPAIR], A2[NPAIR], A3[NPAIR];

    #pragma unroll
    for (int p = 0; p < NPAIR; ++p) {
        const int rp = g + p * T;
        float4 xv = make_float4(0.f, 0.f, 0.f, 0.f);
        yv[p] = make_float4(0.f, 0.f, 0.f, 0.f);
        ev[p] = make_float4(0.f, 0.f, 0.f, 0.f);
        if (rp < n_pairs) {
            xv    = reinterpret_cast<const float4*>(x)[rp];
            yv[p] = reinterpret_cast<const float4*>(y)[rp];
            ev[p] = reinterpret_cast<const float4*>(eps)[rp];
        }
        X0[p].x = xv.x; X0[p].y = xv.z;   // rows 2rp, 2rp+1: x[0]
        X1[p].x = xv.y; X1[p].y = xv.w;   // rows 2rp, 2rp+1: x[1]
        A0[p] = splat(b2_0); A1[p] = splat(b2_1);
        A2[p] = splat(b2_2); A3[p] = splat(b2_3);
    }

    // Main MLP loop: 16 chunks x 4 hidden units. Weight addresses are
    // wave-uniform -> SMEM scalar loads; no LDS, no per-lane VMEM.
    #pragma unroll 2
    for (int c = 0; c < 16; ++c) {
        const float4 wa = *reinterpret_cast<const float4*>(W1 + 4 * c);        // W1[0][4c..]
        const float4 wb = *reinterpret_cast<const float4*>(W1 + 64 + 4 * c);   // W1[1][4c..]
        const float4 bb = *reinterpret_cast<const float4*>(b1 + 4 * c);
        const float4 w2r[4] = {
            reinterpret_cast<const float4*>(W2)[4 * c + 0],
            reinterpret_cast<const float4*>(W2)[4 * c + 1],
            reinterpret_cast<const float4*>(W2)[4 * c + 2],
            reinterpret_cast<const float4*>(W2)[4 * c + 3],
        };
        #pragma unroll
        for (int j = 0; j < 4; ++j) {
            const v2f waj = splat((&wa.x)[j]);
            const v2f wbj = splat((&wb.x)[j]);
            const v2f bj  = splat((&bb.x)[j]);
            const v2f w20 = splat(w2r[j].x);
            const v2f w21 = splat(w2r[j].y);
            const v2f w22 = splat(w2r[j].z);
            const v2f w23 = splat(w2r[j].w);
            #pragma unroll
            for (int p = 0; p < NPAIR; ++p) {
                v2f h = __builtin_elementwise_fma(X1[p], wbj, bj);
                h = __builtin_elementwise_fma(X0[p], waj, h);
                h = __builtin_elementwise_max(h, splat(0.f));
                A0[p] = __builtin_elementwise_fma(h, w20, A0[p]);
                A1[p] = __builtin_elementwise_fma(h, w21, A1[p]);
                A2[p] = __builtin_elementwise_fma(h, w22, A2[p]);
                A3[p] = __builtin_elementwise_fma(h, w23, A3[p]);
            }
        }
    }

    // Epilogue: Lyapunov rescale, rsample, logp (all operands in registers).
    float lsum = 0.f;
    #pragma unroll
    for (int p = 0; p < NPAIR; ++p) {
        const int rp = g + p * T;
        float4 fxv;
        #pragma unroll
        for (int hh = 0; hh < 2; ++hh) {
            const float mu0 = hh ? A0[p].y : A0[p].x;
            const float mu1 = hh ? A1[p].y : A1[p].x;
            const float lv0 = hh ? A2[p].y : A2[p].x;
            const float lv1 = hh ? A3[p].y : A3[p].x;
            const float xx0 = hh ? X0[p].y : X0[p].x;
            const float xx1 = hh ? X1[p].y : X1[p].x;
            const float y0 = hh ? yv[p].z : yv[p].x;
            const float y1 = hh ? yv[p].w : yv[p].y;
            const float e0 = hh ? ev[p].z : ev[p].x;
            const float e1 = hh ? ev[p].w : ev[p].y;
            // V(x), V(mu)
            const float zx0 = fmaf(xx0, wv00, xx1 * wv10);
            const float zx1 = fmaf(xx0, wv01, xx1 * wv11);
            const float Vx  = fmaf(zx0, zx0, fmaf(zx1, zx1, 1e-3f));
            const float zm0 = fmaf(mu0, wv00, mu1 * wv10);
            const float zm1 = fmaf(mu0, wv01, mu1 * wv11);
            const float Vmu = fmaf(zm0, zm0, fmaf(zm1, zm1, 1e-3f));
            // scale = min(beta*Vx, Vmu)/Vmu
            const float scale = fminf(0.99f * Vx, Vmu) * rcp_fast(Vmu);
            const float ms0 = mu0 * scale, ms1 = mu1 * scale;
            // rsample: fx = ms + exp(lv/2)*eps
            const float f0 = fmaf(__expf(0.5f * lv0), e0, ms0);
            const float f1 = fmaf(__expf(0.5f * lv1), e1, ms1);
            if (hh) { fxv.z = f0; fxv.w = f1; }
            else    { fxv.x = f0; fxv.y = f1; }
            // -logp contribution
            const float d0 = y0 - ms0;
            const float d1 = y1 - ms1;
            const float q = fmaf(d0 * d0, __expf(-lv0), d1 * d1 * __expf(-lv1));
            lsum += fmaf(0.5f, q + lv0 + lv1, LOG_2PI);
        }
        if (rp < n_pairs) reinterpret_cast<float4*>(fx_out)[rp] = fxv;
    }

    // reduce lsum: wave shuffle -> LDS -> one partial per block (no atomics)
    #pragma unroll
    for (int off = 32; off; off >>= 1) lsum += __shfl_xor(lsum, off, 64);
    if ((t & 63) == 0) s_part[t >> 6] = lsum;
    __syncthreads();
    if (t == 0) {
        float bs = 0.f;
        #pragma unroll
        for (int w = 0; w < BLOCK / 64; ++w) bs += s_part[w];
        block_part[blockIdx.x] = bs;
    }
}

// Sum GRID per-block partials -> logp_out. One block of 256 threads.
__launch_bounds__(BLOCK, 1)
__global__ void mdn_reduce_kernel(const float* __restrict__ block_part,
                                  float* __restrict__ logp_out)
{
    __shared__ float s_part[BLOCK / 64];
    const int t = threadIdx.x;
    float s = 0.f;
    #pragma unroll
    for (int k = 0; k < GRID / BLOCK; ++k) s += block_part[t + k * BLOCK];
    #pragma unroll
    for (int off = 32; off; off >>= 1) s += __shfl_xor(s, off, 64);
    if ((t & 63) == 0) s_part[t >> 6] = s;
    __syncthreads();
    if (t == 0) {
        float bs = 0.f;
        #pragma unroll
        for (int w = 0; w < BLOCK / 64; ++w) bs += s_part[w];
        *logp_out = bs;
    }
}

extern "C" void kernel_launch(void* const* d_in, const int* in_sizes, int n_in,
                              void* d_out, int out_size, void* d_ws, size_t ws_size,
                              hipStream_t stream) {
    const float* x   = (const float*)d_in[0];
    const float* y   = (const float*)d_in[1];
    const float* eps = (const float*)d_in[2];
    const float* W1  = (const float*)d_in[3];
    const float* b1  = (const float*)d_in[4];
    const float* W2  = (const float*)d_in[5];
    const float* b2  = (const float*)d_in[6];
    const float* Wv  = (const float*)d_in[7];

    const int B = in_sizes[0] / 2;          // rows
    const int n_pairs = B / 2;              // float4 row-pairs
    float* fx_out     = (float*)d_out;
    float* logp_out   = fx_out + (size_t)2 * B;   // scalar at flat index 2B
    float* block_part = (float*)d_ws;             // GRID floats of scratch

    mdn_kernel<<<GRID, BLOCK, 0, stream>>>(x, y, eps, W1, b1, W2, b2, Wv,
                                           fx_out, block_part, n_pairs);
    mdn_reduce_kernel<<<1, BLOCK, 0, stream>>>(block_part, logp_out);
}